// Round 10
// baseline (116.743 us; speedup 1.0000x reference)
//
#include <hip/hip_runtime.h>
#include <hip/hip_bf16.h>

#define CCH 64      // channels
#define NPIX 4096   // 64*64 pooled points

typedef __attribute__((ext_vector_type(8))) short short8;   // 8 bf16 (4 VGPRs)
typedef __attribute__((ext_vector_type(16))) float f32x16;  // MFMA 32x32 accumulator

union U4S8 { uint4 u; short8 s; };

__device__ inline uint32_t pk2bf(float lo, float hi) {
    __hip_bfloat162 h = __float22bfloat162_rn(make_float2(lo, hi));
    return *reinterpret_cast<uint32_t*>(&h);
}
__device__ inline float max3f(float a, float b, float c) {
    return fmaxf(fmaxf(a, b), c);    // fuses to v_max3_f32
}

// ---------------------------------------------------------------------------
// Kernel 1: fused avg-pool 4x4 + 1x1 convs via MFMA.
// Re-tiled for residency: 1024 blocks (8b x 64 prow x 2 half), 256 thr,
// 4 blocks/CU -> 16 waves/CU, 128 KB read per block, 32 loads/thread.
// Block covers 32 pooled points = exactly ONE attn kv-chunk -> VP epilogue
// is one contiguous 4KB store. Same sigma-permuted VP layout as attn.
// ---------------------------------------------------------------------------
__global__ __launch_bounds__(256, 4) void pool_conv_kernel(
    const float* __restrict__ x,
    const float* __restrict__ Wq, const float* __restrict__ bq,
    const float* __restrict__ Wk, const float* __restrict__ bk,
    const float* __restrict__ Wv, const float* __restrict__ bv,
    __hip_bfloat16* __restrict__ Qo, __hip_bfloat16* __restrict__ Ko,
    __hip_bfloat16* __restrict__ VPo)
{
    const int blk  = blockIdx.x;
    const int b    = blk >> 7;
    const int prow = (blk >> 1) & 63;    // pooled row
    const int half = blk & 1;            // pooled col half (32 cols)
    const int t    = threadIdx.x;
    const int lane = t & 63;
    const int w    = t >> 6;
    const int l31  = lane & 31;
    const int hi   = lane >> 5;

    __shared__ __align__(16) __hip_bfloat16 xdt[32][72];    // [pt][ch]
    __shared__ __align__(16) __hip_bfloat16 otile[80][36];  // [oc][pt]
    __shared__ float sbias[96];

    if (t < 96) {
        float v = 0.f;
        if (t < 8)       v = bq[t];
        else if (t < 16) v = bk[t-8];
        else if (t < 80) v = bv[t-16];
        sbias[t] = v;
    }

    // ---- pooling: wave w covers channels w*16..+15; lanes: 32 cols x 2 row-pairs
    // lane(l31,hi): rows prow*4 + hi + {0,2}, cols half*128 + l31*4 .. +3
    const float* xbase = x + (((size_t)(b*CCH))*256 + (size_t)(prow*4 + hi))*256
                           + half*128 + l31*4;
    #pragma unroll
    for (int cc = 0; cc < 16; ++cc) {
        const int c = w*16 + cc;
        const float* xp = xbase + (size_t)c*65536;
        float4 a0 = *(const float4*)(xp);
        float4 a1 = *(const float4*)(xp + 512);    // +2 rows
        float s = (a0.x+a0.y+a0.z+a0.w) + (a1.x+a1.y+a1.z+a1.w);
        s += __shfl_xor(s, 32);                    // combine row pairs
        if (hi == 0) xdt[l31][c] = __float2bfloat16(s * 0.0625f);
    }

    // ---- W fragments (A operand): wave w<3 -> oc-tile oct=w ----
    const int  oct  = w;
    const bool busy = (w < 3);
    short8 wf[4];
    if (busy) {
        const int row = oct*32 + l31;
        const float* wr = nullptr;
        if (row < 8)       wr = Wq + row*CCH;
        else if (row < 16) wr = Wk + (row-8)*CCH;
        else if (row < 80) wr = Wv + (row-16)*CCH;
        #pragma unroll
        for (int kt = 0; kt < 4; ++kt) {
            U4S8 f;
            if (wr) {
                const int c0 = kt*16 + hi*8;
                float4 a = *(const float4*)(wr + c0);
                float4 d = *(const float4*)(wr + c0 + 4);
                f.u.x = pk2bf(a.x, a.y); f.u.y = pk2bf(a.z, a.w);
                f.u.z = pk2bf(d.x, d.y); f.u.w = pk2bf(d.z, d.w);
            } else {
                f.u = make_uint4(0,0,0,0);
            }
            wf[kt] = f.s;
        }
    }

    __syncthreads();

    // ---- B fragments from LDS + MFMA (one 32-pt tile) ----
    if (busy) {
        short8 xf[4];
        #pragma unroll
        for (int kt = 0; kt < 4; ++kt)
            xf[kt] = *(const short8*)&xdt[l31][kt*16 + hi*8];

        f32x16 acc;
        #pragma unroll
        for (int r = 0; r < 16; ++r) acc[r] = 0.f;
        #pragma unroll
        for (int kt = 0; kt < 4; ++kt)
            acc = __builtin_amdgcn_mfma_f32_32x32x16_bf16(wf[kt], xf[kt], acc, 0, 0, 0);

        // stage 1: acc (+bias) -> otile[oc][pt]
        #pragma unroll
        for (int r = 0; r < 16; ++r) {
            const int row = (r&3) + 8*(r>>2) + 4*hi;
            const int oc  = oct*32 + row;
            if (oc < 80) otile[oc][l31] = __float2bfloat16(acc[r] + sbias[oc]);
        }
    }
    __syncthreads();

    // ---- stage 2: coalesced emits ----
    const int i0 = prow*64 + half*32;
    // Q, K: 512B each (32 pts x 8 oc)
    if (t < 64) {
        const int p = t & 31;
        const int oc0 = (t < 32) ? 0 : 8;
        unsigned short v[8];
        #pragma unroll
        for (int j = 0; j < 8; ++j)
            v[j] = *reinterpret_cast<const unsigned short*>(&otile[oc0 + j][p]);
        uint4 q;
        q.x = (uint32_t)v[0] | ((uint32_t)v[1] << 16);
        q.y = (uint32_t)v[2] | ((uint32_t)v[3] << 16);
        q.z = (uint32_t)v[4] | ((uint32_t)v[5] << 16);
        q.w = (uint32_t)v[6] | ((uint32_t)v[7] << 16);
        __hip_bfloat16* dst = (t < 32) ? Qo : Ko;
        *(uint4*)(dst + ((size_t)b*NPIX + i0 + p)*8) = q;
    }
    // VP: block's chunk chg = i0>>5 -> 4 consecutive frags (s1,ct) = 4KB.
    // thread t -> frag f = t>>6 (s1=f>>1, ct=f&1), lane-in-frag l = t&63.
    // sigma element order: h2=0 rows take pt {0-3,8-11}, h2=1 take {4-7,12-15}.
    {
        const int chg = i0 >> 5;
        __hip_bfloat16* vdst = VPo + ((size_t)b*512 + (size_t)chg*4)*512;
        const int f   = t >> 6;
        const int s1  = f >> 1;
        const int ct  = f & 1;
        const int l   = t & 63;
        const int c31 = l & 31;
        const int h2  = l >> 5;
        const int row = 16 + ct*32 + c31;
        const int pt0 = s1*16 + h2*4;
        uint2 a0 = *(const uint2*)&otile[row][pt0];         // j = 0..3
        uint2 a1 = *(const uint2*)&otile[row][pt0 + 8];     // j = 4..7
        *(uint4*)(vdst + t*8) = make_uint4(a0.x, a0.y, a1.x, a1.y);
    }
}

// ---------------------------------------------------------------------------
// Kernel 2: flash attention. 1024 blocks (xcd-mapped: b = blk&7), 256 thr =
// 4 waves = 4 kv-quarters; each block covers 32 queries.
//   S^T = mfma(K_frag, Q_frag): lane (q=l&31) holds 16 of 32 kv scores.
//   PV  = mfma(V_frag(A, sigma-packed), P_frag(B, pure in-lane packs)).
// 4-way kv merge through LDS at the end.
// ---------------------------------------------------------------------------
__global__ __launch_bounds__(256, 4) void attn_kernel(
    const __hip_bfloat16* __restrict__ Q, const __hip_bfloat16* __restrict__ K,
    const __hip_bfloat16* __restrict__ VP, float* __restrict__ OS)
{
    const int bb   = blockIdx.x;
    const int b    = bb & 7;          // XCD-locality: batch per XCD
    const int qg   = bb >> 3;         // 0..127
    const int i0   = qg * 32;
    const int t    = threadIdx.x;
    const int lane = t & 63;
    const int kvq  = t >> 6;          // wave = kv quarter
    const int l31  = lane & 31;
    const int hi   = lane >> 5;

    __shared__ float tiles[4][64][33];
    __shared__ float ml[4][2][32];
    __shared__ float fs[4][32];
    __shared__ float ils[32];

    // Q fragment (B operand): hi=0 lanes hold Q[q=i0+l31][d=0..7], hi=1 zero
    U4S8 qf;
    if (hi == 0) qf.u = *(const uint4*)(Q + ((size_t)b*NPIX + i0 + l31)*8);
    else         qf.u = make_uint4(0,0,0,0);

    f32x16 acc0, acc1, zacc;
    #pragma unroll
    for (int r = 0; r < 16; ++r) { acc0[r] = 0.f; acc1[r] = 0.f; zacc[r] = 0.f; }
    float m = -1e30f, l = 0.f;

    const __hip_bfloat16* Kb  = K  + (size_t)b*NPIX*8;
    const __hip_bfloat16* VPb = VP + (size_t)b*512*512;   // 512 frags x 512 bf16

    auto ldK = [&](int kv) {
        U4S8 r;
        if (hi == 0) r.u = *(const uint4*)(Kb + (size_t)(kv + l31)*8);
        else         r.u = make_uint4(0,0,0,0);
        return r;
    };
    auto ldVP = [&](int chg, int s1, int ct) {
        U4S8 r;
        r.u = *(const uint4*)(VPb + ((size_t)((chg*2 + s1)*2 + ct))*512 + lane*8);
        return r;
    };

    int kv0 = kvq * 1024;
    // prefetch chunk 0
    U4S8 kf = ldK(kv0);
    U4S8 v00 = ldVP(kv0>>5, 0, 0), v10 = ldVP(kv0>>5, 0, 1);
    U4S8 v01 = ldVP(kv0>>5, 1, 0), v11 = ldVP(kv0>>5, 1, 1);

    #pragma unroll 1
    for (int ch = 0; ch < 32; ++ch) {
        U4S8 ckf = kf, cv00 = v00, cv01 = v01, cv10 = v10, cv11 = v11;
        const int nkv0 = kv0 + 32;
        // prefetch next chunk (reads past quarter stay inside d_ws; unused on last iter)
        kf  = ldK(nkv0);
        v00 = ldVP(nkv0>>5, 0, 0); v10 = ldVP(nkv0>>5, 0, 1);
        v01 = ldVP(nkv0>>5, 1, 0); v11 = ldVP(nkv0>>5, 1, 1);

        // S^T: lane holds q=l31, kv rows (r&3)+8*(r>>2)+4*hi of this 32-chunk
        f32x16 s = __builtin_amdgcn_mfma_f32_32x32x16_bf16(ckf.s, qf.s, zacc, 0, 0, 0);

        // row max via max3 tree (T17): 7 instrs for 16 values
        float mx = max3f(s[0], s[1], s[2]);
        mx = max3f(mx, s[3],  s[4]);
        mx = max3f(mx, s[5],  s[6]);
        mx = max3f(mx, s[7],  s[8]);
        mx = max3f(mx, s[9],  s[10]);
        mx = max3f(mx, s[11], s[12]);
        mx = max3f(mx, s[13], s[14]);
        mx = fmaxf(mx, s[15]);
        mx = fmaxf(mx, __shfl_xor(mx, 32));

        // deferred rescale (T13): all acc cols are lane's own query -> plain scale
        if (!__all(mx <= m + 8.f)) {
            float mnew = fmaxf(m, mx);
            float sc = __expf(m - mnew);
            l *= sc; m = mnew;
            #pragma unroll
            for (int r = 0; r < 16; ++r) { acc0[r] *= sc; acc1[r] *= sc; }
        }

        float p[16];
        float ssum = 0.f;
        #pragma unroll
        for (int r = 0; r < 16; ++r) { p[r] = __expf(s[r] - m); ssum += p[r]; }
        ssum += __shfl_xor(ssum, 32);
        l += ssum;

        // B-operand P fragments, sigma-matched to VP packing:
        // pure in-lane cvt_pk packs, no cross-lane ops.
        U4S8 pb0, pb1;
        pb0.u.x = pk2bf(p[0],  p[1]);  pb0.u.y = pk2bf(p[2],  p[3]);
        pb0.u.z = pk2bf(p[4],  p[5]);  pb0.u.w = pk2bf(p[6],  p[7]);
        pb1.u.x = pk2bf(p[8],  p[9]);  pb1.u.y = pk2bf(p[10], p[11]);
        pb1.u.z = pk2bf(p[12], p[13]); pb1.u.w = pk2bf(p[14], p[15]);

        acc0 = __builtin_amdgcn_mfma_f32_32x32x16_bf16(cv00.s, pb0.s, acc0, 0, 0, 0);
        acc1 = __builtin_amdgcn_mfma_f32_32x32x16_bf16(cv10.s, pb0.s, acc1, 0, 0, 0);
        acc0 = __builtin_amdgcn_mfma_f32_32x32x16_bf16(cv01.s, pb1.s, acc0, 0, 0, 0);
        acc1 = __builtin_amdgcn_mfma_f32_32x32x16_bf16(cv11.s, pb1.s, acc1, 0, 0, 0);

        kv0 = nkv0;
    }

    // ---- 4-way kv merge ----
    #pragma unroll
    for (int r = 0; r < 16; ++r) {
        const int cr = (r&3) + 8*(r>>2) + 4*hi;
        tiles[kvq][cr]     [l31] = acc0[r];
        tiles[kvq][cr + 32][l31] = acc1[r];
    }
    if (hi == 0) { ml[kvq][0][l31] = m; ml[kvq][1][l31] = l; }
    __syncthreads();

    if (t < 32) {
        float m0 = ml[0][0][t], m1 = ml[1][0][t], m2 = ml[2][0][t], m3 = ml[3][0][t];
        float ms = fmaxf(fmaxf(m0, m1), fmaxf(m2, m3));
        float f0 = __expf(m0-ms), f1 = __expf(m1-ms), f2 = __expf(m2-ms), f3 = __expf(m3-ms);
        fs[0][t] = f0; fs[1][t] = f1; fs[2][t] = f2; fs[3][t] = f3;
        ils[t] = 1.f / (ml[0][1][t]*f0 + ml[1][1][t]*f1 + ml[2][1][t]*f2 + ml[3][1][t]*f3);
    }
    __syncthreads();

    // combine + write: OS (b, c, n); thread -> (c = t>>2, 8 queries)
    float* outp = OS + (size_t)b*CCH*NPIX + i0;
    const int c  = t >> 2;
    const int q8 = (t & 3) * 8;
    float o[8];
    #pragma unroll
    for (int j = 0; j < 8; ++j) {
        const int q = q8 + j;
        float v = tiles[0][c][q]*fs[0][q] + tiles[1][c][q]*fs[1][q]
                + tiles[2][c][q]*fs[2][q] + tiles[3][c][q]*fs[3][q];
        o[j] = v * ils[q];
    }
    *(float4*)(outp + (size_t)c*NPIX + q8)     = make_float4(o[0], o[1], o[2], o[3]);
    *(float4*)(outp + (size_t)c*NPIX + q8 + 4) = make_float4(o[4], o[5], o[6], o[7]);
}

// ---------------------------------------------------------------------------
// Kernel 3: bilinear x4 upsample (align_corners=True) + gamma*up + x,
// float4-vectorized (4 outputs/thread share h-row).
// ---------------------------------------------------------------------------
__global__ __launch_bounds__(256) void upsample_add_kernel(
    const float* __restrict__ OS, const float* __restrict__ x,
    const float* __restrict__ gamma, float* __restrict__ out)
{
    const size_t qidx = (size_t)blockIdx.x * 256 + threadIdx.x;  // float4 index
    const size_t idx  = qidx * 4;
    const float g = gamma[0];
    const int w4 = (int)(idx & 255);
    const int h  = (int)((idx >> 8) & 255);
    const size_t bc = idx >> 16;

    const float scale = 63.0f / 255.0f;
    float fh = h * scale; int h0 = (int)fh; float fy = fh - (float)h0; int h1 = min(h0+1, 63);

    const float* r0 = OS + bc * (size_t)NPIX + h0*64;
    const float* r1 = OS + bc * (size_t)NPIX + h1*64;
    float4 xi = *(const float4*)(x + idx);

    float o[4];
    #pragma unroll
    for (int j = 0; j < 4; ++j) {
        const int w = w4 + j;
        float fw = w * scale; int w0 = (int)fw; float fx = fw - (float)w0; int w1 = min(w0+1, 63);
        float a0 = r0[w0], a1 = r0[w1], b0 = r1[w0], b1 = r1[w1];
        float vt = a0 + (a1 - a0) * fx;
        float vb = b0 + (b1 - b0) * fx;
        o[j] = vt + (vb - vt) * fy;
    }
    float4 ov;
    ov.x = g*o[0] + xi.x; ov.y = g*o[1] + xi.y;
    ov.z = g*o[2] + xi.z; ov.w = g*o[3] + xi.w;
    *(float4*)(out + idx) = ov;
}

// ---------------------------------------------------------------------------
extern "C" void kernel_launch(void* const* d_in, const int* in_sizes, int n_in,
                              void* d_out, int out_size, void* d_ws, size_t ws_size,
                              hipStream_t stream) {
    const float* x     = (const float*)d_in[0];
    const float* Wq    = (const float*)d_in[1];
    const float* bq    = (const float*)d_in[2];
    const float* Wk    = (const float*)d_in[3];
    const float* bk    = (const float*)d_in[4];
    const float* Wv    = (const float*)d_in[5];
    const float* bv    = (const float*)d_in[6];
    const float* gamma = (const float*)d_in[7];
    float* out = (float*)d_out;

    char* ws = (char*)d_ws;
    __hip_bfloat16* Qb = (__hip_bfloat16*)(ws);                      // 512 KB
    __hip_bfloat16* Kb = (__hip_bfloat16*)(ws + (size_t)( 512<<10)); // 512 KB
    __hip_bfloat16* VP = (__hip_bfloat16*)(ws + (size_t)(1024<<10)); // 4 MB packed
    float*          OS = (float*)         (ws + (size_t)(5120<<10)); // 8 MB

    pool_conv_kernel<<<1024, 256, 0, stream>>>(x, Wq, bq, Wk, bk, Wv, bv, Qb, Kb, VP);
    attn_kernel<<<1024, 256, 0, stream>>>(Qb, Kb, VP, OS);
    const size_t total4 = (size_t)8 * 64 * 256 * 256 / 4;
    upsample_add_kernel<<<(int)(total4 / 256), 256, 0, stream>>>(OS, x, gamma, out);
}